// Round 3
// baseline (4834.151 us; speedup 1.0000x reference)
//
#include <hip/hip_runtime.h>

// Problem constants
#define Sx 256
#define Bx 32
#define Hx 512
#define Gx 2048   // 4H
#define Lx 20
#define Rx 8192   // S*B

typedef __attribute__((ext_vector_type(8))) short short8;
typedef __attribute__((ext_vector_type(4))) float f32x4;
typedef __attribute__((ext_vector_type(16))) float f32x16;

__device__ __forceinline__ unsigned short f2bf(float f) {
  union { float f; unsigned u; } v; v.f = f;
  unsigned u = v.u;
  return (unsigned short)((u + 0x7fffu + ((u >> 16) & 1u)) >> 16);
}
__device__ __forceinline__ float bf2f(unsigned short h) {
  union { unsigned u; float f; } v; v.u = ((unsigned)h) << 16;
  return v.f;
}
__device__ __forceinline__ float bfh(unsigned long long x, int r) {
  return bf2f((unsigned short)((x >> (16 * r)) & 0xffffull));
}
__device__ __forceinline__ float sigmf(float x) { return 1.0f / (1.0f + expf(-x)); }

// ---------------- pack / cast kernels ----------------

__global__ void k_pack_x(const float* __restrict__ x, unsigned short* __restrict__ xbf) {
  int tid = blockIdx.x * 256 + threadIdx.x;      // 0 .. S*B*H-1
  int h = tid & (Hx - 1);
  int r = tid >> 9;          // t*32+b
  int b = r & 31;
  int t = r >> 5;
  xbf[tid] = f2bf(x[(b * Sx + t) * Hx + h]);
}

__global__ void k_cast(const float* __restrict__ s, unsigned short* __restrict__ d, int n) {
  int i = blockIdx.x * 256 + threadIdx.x;
  if (i < n) d[i] = f2bf(s[i]);
}

__global__ void k_add2(const float* __restrict__ a, const float* __restrict__ b,
                       float* __restrict__ o, int n) {
  int i = blockIdx.x * 256 + threadIdx.x;
  if (i < n) o[i] = a[i] + b[i];
}

// ---------------- GEMM: C[M,N](bf16) = A[M,K](bf16) * Bw[N,K]^T(bf16) + bias[N] ----------------
__global__ __launch_bounds__(256) void k_gemm(
    const unsigned short* __restrict__ A,
    const unsigned short* __restrict__ Bw,
    const float* __restrict__ bias,
    unsigned short* __restrict__ C,
    int M, int N, int K)
{
  const int bn = blockIdx.x, bm = blockIdx.y;
  const int tid = threadIdx.x;
  const int w = tid >> 6, lane = tid & 63;
  const int wr = w >> 1, wc = w & 1;
  const int lo = lane & 15, qd = lane >> 4;

  __shared__ unsigned short As[128 * 72];
  __shared__ unsigned short Bs[128 * 72];

  f32x4 acc[4][4] = {};

  const int ktn = K >> 6;
  for (int kt = 0; kt < ktn; ++kt) {
    __syncthreads();
#pragma unroll
    for (int p = 0; p < 4; ++p) {
      int c = tid + (p << 8);
      int row = c >> 3, kc = c & 7;
      *(short8*)&As[row * 72 + kc * 8] =
          *(const short8*)&A[(size_t)(bm * 128 + row) * K + kt * 64 + kc * 8];
      *(short8*)&Bs[row * 72 + kc * 8] =
          *(const short8*)&Bw[(size_t)(bn * 128 + row) * K + kt * 64 + kc * 8];
    }
    __syncthreads();
#pragma unroll
    for (int kk = 0; kk < 2; ++kk) {
      short8 af[4], bfr[4];
#pragma unroll
      for (int mi = 0; mi < 4; ++mi)
        af[mi] = *(const short8*)&As[(wr * 64 + mi * 16 + lo) * 72 + kk * 32 + qd * 8];
#pragma unroll
      for (int ni = 0; ni < 4; ++ni)
        bfr[ni] = *(const short8*)&Bs[(wc * 64 + ni * 16 + lo) * 72 + kk * 32 + qd * 8];
#pragma unroll
      for (int mi = 0; mi < 4; ++mi)
#pragma unroll
        for (int ni = 0; ni < 4; ++ni)
          acc[mi][ni] = __builtin_amdgcn_mfma_f32_16x16x32_bf16(af[mi], bfr[ni], acc[mi][ni], 0, 0, 0);
    }
  }
#pragma unroll
  for (int mi = 0; mi < 4; ++mi) {
#pragma unroll
    for (int ni = 0; ni < 4; ++ni) {
      int n = bn * 128 + wc * 64 + ni * 16 + lo;
      float bv = bias[n];
#pragma unroll
      for (int r = 0; r < 4; ++r) {
        int m = bm * 128 + wr * 64 + mi * 16 + qd * 4 + r;
        C[(size_t)m * N + n] = f2bf(acc[mi][ni][r] + bv);
      }
    }
  }
}

// ---------------- persistent bidirectional LSTM recurrence (v3) ----------------
// 64 WGs x 64 threads. dir = wg>>5, slice ws = wg&31 owns j in [ws*16, ws*16+16).
// MFMA 32x32x16: C = W_slice[64 gate-rows] x h_prev^T[32 batches].
// Sync protocol (no cache-maintenance ops):
//   - h handoff via relaxed AGENT atomic u64 loads/stores (sc1: LLC-coherent,
//     bypasses non-coherent L1/L2) -> no buffer_inv / buffer_wbl2 ever.
//   - writer: s_waitcnt vmcnt(0) (drains sc1 stores to LLC) then relaxed
//     fetch_add on a per-step counter slot (64B stride).
//   - reader: relaxed poll of the slot; compiler barrier; sc1 data loads.
//     Wave issues in order -> loads cannot pass the poll in hardware.
// LDS swizzle: chunk lc of row rr at pc=(lc&56)|((((lc&7)+(rr>>3))&7)^(rr&7));
// exact 8-per-bank-group balance for both preload writes and MFMA reads.
__global__ __launch_bounds__(64) void k_lstm(
    const unsigned short* __restrict__ xwF,   // [S*B, 2048] bf16 (x@Wih^T + biases)
    const unsigned short* __restrict__ xwB,
    const unsigned short* __restrict__ whF,   // [2048, 512] bf16
    const unsigned short* __restrict__ whB,
    unsigned short* __restrict__ hout,        // [S*B, 1024] bf16 (fwd 0..511, bwd 512..1023)
    unsigned int* __restrict__ ctrs)          // [2][Sx][16] u32, zeroed
{
  const int wg = blockIdx.x;
  const int dir = wg >> 5;
  const int ws = wg & 31;
  const int j0 = ws * 16;
  const unsigned short* xw = dir ? xwB : xwF;
  const unsigned short* wh = dir ? whB : whF;
  unsigned int* ctr = ctrs + dir * (Sx * 16);

  const int lane = threadIdx.x;   // 0..63
  const int bn = lane & 31;       // batch
  const int q  = lane >> 5;       // 0/1

  __shared__ unsigned short Ws[64 * 512];   // 64KB

  // preload: LDS row rr <- W row g = (rr>>4)*512 + j0 + (rr&15); swizzled chunks
  for (int rr = 0; rr < 64; ++rr) {
    int g = ((rr >> 4) << 9) + j0 + (rr & 15);
    int pc = (lane & 56) | ((((lane & 7) + (rr >> 3)) & 7) ^ (rr & 7));
    *(short8*)&Ws[rr * 512 + pc * 8] = *(const short8*)&wh[(size_t)g * Hx + lane * 8];
  }
  __syncthreads();

  float cst[2][4] = {};

  for (int s = 0; s < Sx; ++s) {
    const int t = dir ? (Sx - 1 - s) : s;

    // prefetch xw (read-only, L2-cached plain loads) before the poll
    const unsigned short* xwt = xw + ((size_t)t * Bx + bn) * Gx + j0 + q * 4;
    unsigned long long xg[4][2];
#pragma unroll
    for (int c = 0; c < 4; ++c)
#pragma unroll
      for (int jg = 0; jg < 2; ++jg)
        xg[c][jg] = *(const unsigned long long*)(xwt + c * 512 + jg * 8);
    __asm__ __volatile__("" ::: "memory");

    f32x16 acc0 = {};
    f32x16 acc1 = {};

    if (s > 0) {
      const unsigned int* cp = ctr + (s - 1) * 16;
      while (__hip_atomic_load(cp, __ATOMIC_RELAXED, __HIP_MEMORY_SCOPE_AGENT) < 32u)
        __builtin_amdgcn_s_sleep(1);
      __asm__ __volatile__("" ::: "memory");

      const int tp = dir ? (t + 1) : (t - 1);
      const unsigned short* hb = hout + ((size_t)tp * Bx + bn) * 1024 + dir * Hx + q * 8;
#pragma unroll
      for (int ks = 0; ks < 32; ++ks) {
        union { unsigned long long u[2]; short8 v; } bu;
        bu.u[0] = __hip_atomic_load((const unsigned long long*)(hb + ks * 16),
                                    __ATOMIC_RELAXED, __HIP_MEMORY_SCOPE_AGENT);
        bu.u[1] = __hip_atomic_load((const unsigned long long*)(hb + ks * 16 + 4),
                                    __ATOMIC_RELAXED, __HIP_MEMORY_SCOPE_AGENT);
        int lc = ks * 2 + q;
        int pc0 = (lc & 56) | ((((lc & 7) + (bn >> 3)) & 7) ^ (bn & 7));
        int pc1 = (lc & 56) | ((((lc & 7) + ((32 + bn) >> 3)) & 7) ^ (bn & 7));
        short8 af0 = *(const short8*)&Ws[bn * 512 + pc0 * 8];          // rows 0..31 (i,f low)
        short8 af1 = *(const short8*)&Ws[(32 + bn) * 512 + pc1 * 8];   // rows 32..63 (g,o)
        acc0 = __builtin_amdgcn_mfma_f32_32x32x16_bf16(af0, bu.v, acc0, 0, 0, 0);
        acc1 = __builtin_amdgcn_mfma_f32_32x32x16_bf16(af1, bu.v, acc1, 0, 0, 0);
      }
    }

    // epilogue: lane computes h for batch bn, j = j0 + jg*8 + q*4 + r
    unsigned short* hw = hout + ((size_t)t * Bx + bn) * 1024 + dir * Hx + j0;
#pragma unroll
    for (int jg = 0; jg < 2; ++jg) {
      unsigned long long hv = 0;
#pragma unroll
      for (int r = 0; r < 4; ++r) {
        float iv = acc0[jg * 4 + r]     + bfh(xg[0][jg], r);
        float fv = acc0[8 + jg * 4 + r] + bfh(xg[1][jg], r);
        float gv = acc1[jg * 4 + r]     + bfh(xg[2][jg], r);
        float ov = acc1[8 + jg * 4 + r] + bfh(xg[3][jg], r);
        float ct = sigmf(fv) * cst[jg][r] + sigmf(iv) * tanhf(gv);
        cst[jg][r] = ct;
        float hvf = sigmf(ov) * tanhf(ct);
        hv |= (unsigned long long)f2bf(hvf) << (16 * r);
      }
      __hip_atomic_store((unsigned long long*)(hw + jg * 8 + q * 4), hv,
                         __ATOMIC_RELAXED, __HIP_MEMORY_SCOPE_AGENT);
    }

    // drain sc1 stores to the coherence point, then publish (relaxed is enough:
    // stores are write-through, nothing dirty in L2 to flush)
    __asm__ __volatile__("s_waitcnt vmcnt(0)" ::: "memory");
    if (lane == 0)
      __hip_atomic_fetch_add(ctr + s * 16, 1u, __ATOMIC_RELAXED, __HIP_MEMORY_SCOPE_AGENT);
  }
}

// ---------------- FC ----------------
__global__ __launch_bounds__(256) void k_fc(
    const unsigned short* __restrict__ h1,   // [8192,1024] bf16
    const float* __restrict__ fcw,           // [20,1024]
    const float* __restrict__ fcb,           // [20]
    float* __restrict__ logits)              // [8192,20]
{
  int row = blockIdx.x;
  int l = threadIdx.x & 31;
  int sl = threadIdx.x >> 5;   // 0..7
  __shared__ float red[8][32];
  float p = 0.f;
  if (l < Lx) {
    const unsigned short* hr = h1 + (size_t)row * 1024 + sl * 128;
    const float* wr = fcw + l * 1024 + sl * 128;
#pragma unroll 8
    for (int k = 0; k < 128; ++k) p += bf2f(hr[k]) * wr[k];
  }
  red[sl][l] = p;
  __syncthreads();
  if (threadIdx.x < Lx) {
    float s = fcb[threadIdx.x];
#pragma unroll
    for (int i = 0; i < 8; ++i) s += red[i][threadIdx.x];
    logits[(size_t)row * Lx + threadIdx.x] = s;
  }
}

// ---------------- CRF ----------------
__global__ __launch_bounds__(64) void k_crf(
    const float* __restrict__ logits,   // [(t*32+b)*20 + l]
    const int* __restrict__ labels,     // [B,S]
    const int* __restrict__ mask,       // [B,S]
    const float* __restrict__ trans,    // [20,20]
    const float* __restrict__ startv,
    const float* __restrict__ endv,
    float* __restrict__ out)
{
  int b = blockIdx.x;
  int tid = threadIdx.x;
  __shared__ float tr[Lx * Lx];
  __shared__ float al[2][Lx];
  __shared__ float norm_s;
  for (int i = tid; i < Lx * Lx; i += 64) tr[i] = trans[i];
  if (tid < Lx) al[0][tid] = logits[b * Lx + tid] + startv[tid];
  __syncthreads();
  int cur = 0;
  for (int t = 1; t < Sx; ++t) {
    if (tid < Lx) {
      int to = tid;
      float v[Lx];
      float mx = -1e30f;
#pragma unroll
      for (int f = 0; f < Lx; ++f) { v[f] = al[cur][f] + tr[f * Lx + to]; mx = fmaxf(mx, v[f]); }
      float sum = 0.f;
#pragma unroll
      for (int f = 0; f < Lx; ++f) sum += expf(v[f] - mx);
      float nv = mx + logf(sum) + logits[((size_t)t * Bx + b) * Lx + to];
      int m = mask[b * Sx + t];
      al[1 - cur][to] = (m > 0) ? nv : al[cur][to];
    }
    __syncthreads();
    cur ^= 1;
  }
  if (tid == 0) {
    float mx = -1e30f;
    for (int l = 0; l < Lx; ++l) mx = fmaxf(mx, al[cur][l] + endv[l]);
    float s = 0.f;
    for (int l = 0; l < Lx; ++l) s += expf(al[cur][l] + endv[l] - mx);
    norm_s = mx + logf(s);
  }
  __syncthreads();
  const int* lab = labels + b * Sx;
  const int* msk = mask + b * Sx;
  float part = 0.f;
  int msum = 0;
  for (int t = tid; t < Sx; t += 64) {
    int m = msk[t];
    int tg = lab[t];
    if (m > 0) {
      part += logits[((size_t)t * Bx + b) * Lx + tg];
      if (t >= 1) part += tr[lab[t - 1] * Lx + tg];
      msum++;
    }
  }
#pragma unroll
  for (int o = 32; o > 0; o >>= 1) {
    part += __shfl_down(part, o, 64);
    msum += __shfl_down(msum, o, 64);
  }
  if (tid == 0) {
    float gold = part + startv[lab[0]] + endv[lab[msum - 1]];
    atomicAdd(out, (norm_s - gold) * (1.0f / 32.0f));
  }
}

// ---------------- launch ----------------

extern "C" void kernel_launch(void* const* d_in, const int* in_sizes, int n_in,
                              void* d_out, int out_size, void* d_ws, size_t ws_size,
                              hipStream_t stream)
{
  const float* x      = (const float*)d_in[0];
  const int* labels   = (const int*)d_in[1];
  const int* mask     = (const int*)d_in[2];
  const float* wih0f  = (const float*)d_in[3];
  const float* whh0f  = (const float*)d_in[4];
  const float* bih0f  = (const float*)d_in[5];
  const float* bhh0f  = (const float*)d_in[6];
  const float* wih0b  = (const float*)d_in[7];
  const float* whh0b  = (const float*)d_in[8];
  const float* bih0b  = (const float*)d_in[9];
  const float* bhh0b  = (const float*)d_in[10];
  const float* wih1f  = (const float*)d_in[11];
  const float* whh1f  = (const float*)d_in[12];
  const float* bih1f  = (const float*)d_in[13];
  const float* bhh1f  = (const float*)d_in[14];
  const float* wih1b  = (const float*)d_in[15];
  const float* whh1b  = (const float*)d_in[16];
  const float* bih1b  = (const float*)d_in[17];
  const float* bhh1b  = (const float*)d_in[18];
  const float* fcw    = (const float*)d_in[19];
  const float* fcb    = (const float*)d_in[20];
  const float* transm = (const float*)d_in[21];
  const float* startv = (const float*)d_in[22];
  const float* endv   = (const float*)d_in[23];

  char* p = (char*)d_ws;
  auto alloc = [&](size_t bytes) -> char* {
    char* r = p;
    p += (bytes + 255) & ~((size_t)255);
    return r;
  };

  unsigned short* x_bf    = (unsigned short*)alloc((size_t)Rx * Hx * 2);
  unsigned short* wih0f_b = (unsigned short*)alloc((size_t)Gx * Hx * 2);
  unsigned short* wih0b_b = (unsigned short*)alloc((size_t)Gx * Hx * 2);
  unsigned short* whh0f_b = (unsigned short*)alloc((size_t)Gx * Hx * 2);
  unsigned short* whh0b_b = (unsigned short*)alloc((size_t)Gx * Hx * 2);
  unsigned short* wih1f_b = (unsigned short*)alloc((size_t)Gx * 1024 * 2);
  unsigned short* wih1b_b = (unsigned short*)alloc((size_t)Gx * 1024 * 2);
  unsigned short* whh1f_b = (unsigned short*)alloc((size_t)Gx * Hx * 2);
  unsigned short* whh1b_b = (unsigned short*)alloc((size_t)Gx * Hx * 2);
  float* bias0f = (float*)alloc(Gx * 4);
  float* bias0b = (float*)alloc(Gx * 4);
  float* bias1f = (float*)alloc(Gx * 4);
  float* bias1b = (float*)alloc(Gx * 4);
  unsigned short* xw_f = (unsigned short*)alloc((size_t)Rx * Gx * 2);
  unsigned short* xw_b = (unsigned short*)alloc((size_t)Rx * Gx * 2);
  unsigned short* h0   = (unsigned short*)alloc((size_t)Rx * 1024 * 2);
  unsigned short* h1   = (unsigned short*)alloc((size_t)Rx * 1024 * 2);
  float* logits = (float*)alloc((size_t)Rx * Lx * 4);
  unsigned int* ctrs = (unsigned int*)alloc(2 * 2 * Sx * 16 * 4);  // 2 layers x [2][Sx][16] u32

  if ((size_t)(p - (char*)d_ws) > ws_size) return;

  hipMemsetAsync(ctrs, 0, 2 * 2 * Sx * 16 * 4, stream);

  // pack & cast
  k_pack_x<<<(Rx * Hx) / 256, 256, 0, stream>>>(x, x_bf);
  k_cast<<<(Gx * Hx) / 256, 256, 0, stream>>>(wih0f, wih0f_b, Gx * Hx);
  k_cast<<<(Gx * Hx) / 256, 256, 0, stream>>>(wih0b, wih0b_b, Gx * Hx);
  k_cast<<<(Gx * Hx) / 256, 256, 0, stream>>>(whh0f, whh0f_b, Gx * Hx);
  k_cast<<<(Gx * Hx) / 256, 256, 0, stream>>>(whh0b, whh0b_b, Gx * Hx);
  k_cast<<<(Gx * 1024) / 256, 256, 0, stream>>>(wih1f, wih1f_b, Gx * 1024);
  k_cast<<<(Gx * 1024) / 256, 256, 0, stream>>>(wih1b, wih1b_b, Gx * 1024);
  k_cast<<<(Gx * Hx) / 256, 256, 0, stream>>>(whh1f, whh1f_b, Gx * Hx);
  k_cast<<<(Gx * Hx) / 256, 256, 0, stream>>>(whh1b, whh1b_b, Gx * Hx);
  k_add2<<<Gx / 256, 256, 0, stream>>>(bih0f, bhh0f, bias0f, Gx);
  k_add2<<<Gx / 256, 256, 0, stream>>>(bih0b, bhh0b, bias0b, Gx);
  k_add2<<<Gx / 256, 256, 0, stream>>>(bih1f, bhh1f, bias1f, Gx);
  k_add2<<<Gx / 256, 256, 0, stream>>>(bih1b, bhh1b, bias1b, Gx);

  // layer 0
  k_gemm<<<dim3(Gx / 128, Rx / 128), 256, 0, stream>>>(x_bf, wih0f_b, bias0f, xw_f, Rx, Gx, Hx);
  k_gemm<<<dim3(Gx / 128, Rx / 128), 256, 0, stream>>>(x_bf, wih0b_b, bias0b, xw_b, Rx, Gx, Hx);
  k_lstm<<<64, 64, 0, stream>>>(xw_f, xw_b, whh0f_b, whh0b_b, h0, ctrs);

  // layer 1
  k_gemm<<<dim3(Gx / 128, Rx / 128), 256, 0, stream>>>(h0, wih1f_b, bias1f, xw_f, Rx, Gx, 1024);
  k_gemm<<<dim3(Gx / 128, Rx / 128), 256, 0, stream>>>(h0, wih1b_b, bias1b, xw_b, Rx, Gx, 1024);
  k_lstm<<<64, 64, 0, stream>>>(xw_f, xw_b, whh1f_b, whh1b_b, h1, ctrs + 2 * Sx * 16);

  // FC + CRF
  k_fc<<<Rx, 256, 0, stream>>>(h1, fcw, fcb, logits);
  hipMemsetAsync(d_out, 0, 4, stream);
  k_crf<<<Bx, 64, 0, stream>>>(logits, labels, mask, transm, startv, endv, (float*)d_out);
}

// Round 4
// 4504.274 us; speedup vs baseline: 1.0732x; 1.0732x over previous
//
#include <hip/hip_runtime.h>

// Problem constants
#define Sx 256
#define Bx 32
#define Hx 512
#define Gx 2048   // 4H
#define Lx 20
#define Rx 8192   // S*B

typedef __attribute__((ext_vector_type(8))) short short8;
typedef __attribute__((ext_vector_type(4))) float f32x4;
typedef __attribute__((ext_vector_type(16))) float f32x16;

__device__ __forceinline__ unsigned short f2bf(float f) {
  union { float f; unsigned u; } v; v.f = f;
  unsigned u = v.u;
  return (unsigned short)((u + 0x7fffu + ((u >> 16) & 1u)) >> 16);
}
__device__ __forceinline__ float bf2f(unsigned short h) {
  union { unsigned u; float f; } v; v.u = ((unsigned)h) << 16;
  return v.f;
}
__device__ __forceinline__ float bfh(unsigned long long x, int r) {
  return bf2f((unsigned short)((x >> (16 * r)) & 0xffffull));
}
__device__ __forceinline__ float sigmf(float x) { return 1.0f / (1.0f + expf(-x)); }

// ---------------- pack / cast kernels ----------------

__global__ void k_pack_x(const float* __restrict__ x, unsigned short* __restrict__ xbf) {
  int tid = blockIdx.x * 256 + threadIdx.x;      // 0 .. S*B*H-1
  int h = tid & (Hx - 1);
  int r = tid >> 9;          // t*32+b
  int b = r & 31;
  int t = r >> 5;
  xbf[tid] = f2bf(x[(b * Sx + t) * Hx + h]);
}

__global__ void k_cast(const float* __restrict__ s, unsigned short* __restrict__ d, int n) {
  int i = blockIdx.x * 256 + threadIdx.x;
  if (i < n) d[i] = f2bf(s[i]);
}

__global__ void k_add2(const float* __restrict__ a, const float* __restrict__ b,
                       float* __restrict__ o, int n) {
  int i = blockIdx.x * 256 + threadIdx.x;
  if (i < n) o[i] = a[i] + b[i];
}

// hT [dir][t][ktile=64][b=32][8] -> rows [(t*32+b)][dir*512 + kt*8 + e]
__global__ void k_repack(const unsigned short* __restrict__ hT, unsigned short* __restrict__ rows) {
  int tid = blockIdx.x * 256 + threadIdx.x;   // (dir,t,kt,b), b fastest; 2*256*64*32 = 1M
  int b = tid & 31;
  int kt = (tid >> 5) & 63;
  int t = (tid >> 11) & 255;
  int dir = tid >> 19;
  short8 v = *(const short8*)&hT[(size_t)tid * 8];
  *(short8*)&rows[((size_t)(t * 32 + b)) * 1024 + dir * 512 + kt * 8] = v;
}

// ---------------- GEMM: xw[perm(n)][m] = A[M,K] * Bw[N,K]^T + bias[N] ----------------
// Output layout permuted for k_lstm: elem(n,m) at ws*(Rx*64) + m*64 + c*16 + jl,
// where ws=(n>>4)&31, c=n>>9, jl=n&15 (per-WG-contiguous xw blocks).
__global__ __launch_bounds__(256) void k_gemm(
    const unsigned short* __restrict__ A,
    const unsigned short* __restrict__ Bw,
    const float* __restrict__ bias,
    unsigned short* __restrict__ C,
    int M, int N, int K)
{
  const int bn = blockIdx.x, bm = blockIdx.y;
  const int tid = threadIdx.x;
  const int w = tid >> 6, lane = tid & 63;
  const int wr = w >> 1, wc = w & 1;
  const int lo = lane & 15, qd = lane >> 4;

  __shared__ unsigned short As[128 * 72];
  __shared__ unsigned short Bs[128 * 72];

  f32x4 acc[4][4] = {};

  const int ktn = K >> 6;
  for (int kt = 0; kt < ktn; ++kt) {
    __syncthreads();
#pragma unroll
    for (int p = 0; p < 4; ++p) {
      int c = tid + (p << 8);
      int row = c >> 3, kc = c & 7;
      *(short8*)&As[row * 72 + kc * 8] =
          *(const short8*)&A[(size_t)(bm * 128 + row) * K + kt * 64 + kc * 8];
      *(short8*)&Bs[row * 72 + kc * 8] =
          *(const short8*)&Bw[(size_t)(bn * 128 + row) * K + kt * 64 + kc * 8];
    }
    __syncthreads();
#pragma unroll
    for (int kk = 0; kk < 2; ++kk) {
      short8 af[4], bfr[4];
#pragma unroll
      for (int mi = 0; mi < 4; ++mi)
        af[mi] = *(const short8*)&As[(wr * 64 + mi * 16 + lo) * 72 + kk * 32 + qd * 8];
#pragma unroll
      for (int ni = 0; ni < 4; ++ni)
        bfr[ni] = *(const short8*)&Bs[(wc * 64 + ni * 16 + lo) * 72 + kk * 32 + qd * 8];
#pragma unroll
      for (int mi = 0; mi < 4; ++mi)
#pragma unroll
        for (int ni = 0; ni < 4; ++ni)
          acc[mi][ni] = __builtin_amdgcn_mfma_f32_16x16x32_bf16(af[mi], bfr[ni], acc[mi][ni], 0, 0, 0);
    }
  }
#pragma unroll
  for (int mi = 0; mi < 4; ++mi) {
#pragma unroll
    for (int ni = 0; ni < 4; ++ni) {
      int n = bn * 128 + wc * 64 + ni * 16 + lo;
      float bv = bias[n];
      int wsb = (n >> 4) & 31, cg = n >> 9, jl = n & 15;
      size_t base = (size_t)wsb * (Rx * 64) + (size_t)cg * 16 + jl;
#pragma unroll
      for (int r = 0; r < 4; ++r) {
        int m = bm * 128 + wr * 64 + mi * 16 + qd * 4 + r;
        C[base + (size_t)m * 64] = f2bf(acc[mi][ni][r] + bv);
      }
    }
  }
}

// ---------------- persistent bidirectional LSTM recurrence (v4) ----------------
// 64 WGs x 64 threads. dir = wg>>5, slice ws = wg&31 owns j in [ws*16, ws*16+16).
// MFMA 32x32x16: C = W_slice[64 gate-rows] x h_prev^T[32 batches].
// hT layout per dir: [t][ktile=64][batch=32][8] bf16 -> B-frag is one lane-linear
// coalesced b128 PLAIN load per MFMA pair (L2-cached; safe: kernel-start acquire
// invalidates L2, every hT line first touched only after publish).
// xw per-WG blocks: [ws][row=t*32+b][64] -> 4KB contiguous per WG per step.
// Sync: per-WG flag (128B stride) stored sc1 after vmcnt(0) drain of sc1 h-stores;
// readers ballot-poll 32 flags (no RMW contention).
__global__ __launch_bounds__(64) void k_lstm(
    const unsigned short* __restrict__ xwF,   // [32 ws][8192][64] bf16 (permuted xw+bias)
    const unsigned short* __restrict__ xwB,
    const unsigned short* __restrict__ whF,   // [2048, 512] bf16
    const unsigned short* __restrict__ whB,
    unsigned short* __restrict__ hT,          // [2][256][16384] bf16 tiled
    unsigned int* __restrict__ flags)         // [2][32][32] u32, zeroed
{
  const int wg = blockIdx.x;
  const int dir = wg >> 5;
  const int ws = wg & 31;
  const int j0 = ws * 16;
  const unsigned short* xw = (dir ? xwB : xwF) + (size_t)ws * (Rx * 64);
  const unsigned short* wh = dir ? whB : whF;
  unsigned short* hTd = hT + (size_t)dir * (Sx * 16384);
  unsigned int* fl = flags + dir * 32 * 32;

  const int lane = threadIdx.x;   // 0..63
  const int bn = lane & 31;       // batch / MFMA n / A-row m
  const int q  = lane >> 5;       // 0/1

  __shared__ unsigned short Ws[64 * 512];   // 64KB

  // preload: LDS row rr <- W row g = (rr>>4)*512 + j0 + (rr&15); XOR-swizzled chunks
  for (int rr = 0; rr < 64; ++rr) {
    int g = ((rr >> 4) << 9) + j0 + (rr & 15);
    int pc = lane ^ (rr & 7);
    *(short8*)&Ws[rr * 512 + pc * 8] = *(const short8*)&wh[(size_t)g * Hx + lane * 8];
  }
  __syncthreads();

  float cst[2][4] = {};

  for (int s = 0; s < Sx; ++s) {
    const int t = dir ? (Sx - 1 - s) : s;

    // prefetch xw (contiguous per-WG block; plain L2-cached loads) before the poll
    const unsigned short* xwt = xw + ((size_t)t * 32 + bn) * 64 + q * 4;
    unsigned long long xg[4][2];
#pragma unroll
    for (int c = 0; c < 4; ++c)
#pragma unroll
      for (int jg = 0; jg < 2; ++jg)
        xg[c][jg] = *(const unsigned long long*)(xwt + c * 16 + jg * 8);
    __asm__ __volatile__("" ::: "memory");

    f32x16 acc0 = {};
    f32x16 acc1 = {};

    if (s > 0) {
      const unsigned tgt = (unsigned)s;
      for (;;) {
        unsigned v = __hip_atomic_load(fl + (lane & 31) * 32,
                                       __ATOMIC_RELAXED, __HIP_MEMORY_SCOPE_AGENT);
        if (__all((int)(v >= tgt))) break;
      }
      __asm__ __volatile__("" ::: "memory");

      const int tp = dir ? (t + 1) : (t - 1);
      const unsigned short* hb = hTd + (size_t)tp * 16384 + lane * 8;
#pragma unroll
      for (int ks = 0; ks < 32; ++ks) {
        short8 bfr = *(const short8*)(hb + ks * 512);   // lane-linear coalesced 16B
        int lc = ks * 2 + q;
        int pc = lc ^ (bn & 7);
        short8 af0 = *(const short8*)&Ws[bn * 512 + pc * 8];          // gate rows 0..31 (i,f)
        short8 af1 = *(const short8*)&Ws[(32 + bn) * 512 + pc * 8];   // gate rows 32..63 (g,o)
        acc0 = __builtin_amdgcn_mfma_f32_32x32x16_bf16(af0, bfr, acc0, 0, 0, 0);
        acc1 = __builtin_amdgcn_mfma_f32_32x32x16_bf16(af1, bfr, acc1, 0, 0, 0);
      }
    }

    // epilogue: lane (bn,q) computes h for batch bn, j = j0 + jg*8 + q*4 + r
#pragma unroll
    for (int jg = 0; jg < 2; ++jg) {
      unsigned long long hv = 0;
#pragma unroll
      for (int r = 0; r < 4; ++r) {
        float iv = acc0[jg * 4 + r]     + bfh(xg[0][jg], r);
        float fv = acc0[8 + jg * 4 + r] + bfh(xg[1][jg], r);
        float gv = acc1[jg * 4 + r]     + bfh(xg[2][jg], r);
        float ov = acc1[8 + jg * 4 + r] + bfh(xg[3][jg], r);
        float ct = sigmf(fv) * cst[jg][r] + sigmf(iv) * tanhf(gv);
        cst[jg][r] = ct;
        float hvf = sigmf(ov) * tanhf(ct);
        hv |= (unsigned long long)f2bf(hvf) << (16 * r);
      }
      // hT[t][j0/8+jg][bn][q*4..q*4+3] — write-through to LLC
      unsigned short* hw = hTd + (size_t)t * 16384 + ((size_t)(j0 / 8 + jg) * 32 + bn) * 8 + q * 4;
      __hip_atomic_store((unsigned long long*)hw, hv,
                         __ATOMIC_RELAXED, __HIP_MEMORY_SCOPE_AGENT);
    }

    // drain sc1 stores to coherence point, then publish own flag (no RMW)
    __asm__ __volatile__("s_waitcnt vmcnt(0)" ::: "memory");
    if (lane == 0)
      __hip_atomic_store(fl + ws * 32, (unsigned)(s + 1),
                         __ATOMIC_RELAXED, __HIP_MEMORY_SCOPE_AGENT);
  }
}

// ---------------- FC: logits[row,l] = dot(h1T[row,:1024], fc_w[l,:]) + fc_b[l] ----------------
__global__ __launch_bounds__(256) void k_fc(
    const unsigned short* __restrict__ h1T,  // [2][256][16384] tiled
    const float* __restrict__ fcw,           // [20,1024]
    const float* __restrict__ fcb,           // [20]
    float* __restrict__ logits)              // [8192,20]
{
  int row = blockIdx.x;
  int t = row >> 5, b = row & 31;
  int l = threadIdx.x & 31;
  int sl = threadIdx.x >> 5;   // 0..7
  __shared__ float red[8][32];
  float p = 0.f;
  if (l < Lx) {
#pragma unroll 4
    for (int kt = sl * 16; kt < sl * 16 + 16; ++kt) {   // 8-elem groups, k = kt*8
      int k = kt * 8;
      int dir = k >> 9, kk = k & 511;
      const unsigned short* hp = h1T + (size_t)dir * (Sx * 16384) + (size_t)t * 16384
                                 + ((size_t)(kk >> 3) * 32 + b) * 8;
      const float* wr = fcw + l * 1024 + k;
#pragma unroll
      for (int e = 0; e < 8; ++e) p += bf2f(hp[e]) * wr[e];
    }
  }
  red[sl][l] = p;
  __syncthreads();
  if (threadIdx.x < Lx) {
    float s = fcb[threadIdx.x];
#pragma unroll
    for (int i = 0; i < 8; ++i) s += red[i][threadIdx.x];
    logits[(size_t)row * Lx + threadIdx.x] = s;
  }
}

// ---------------- CRF ----------------
__global__ __launch_bounds__(64) void k_crf(
    const float* __restrict__ logits,   // [(t*32+b)*20 + l]
    const int* __restrict__ labels,     // [B,S]
    const int* __restrict__ mask,       // [B,S]
    const float* __restrict__ trans,    // [20,20]
    const float* __restrict__ startv,
    const float* __restrict__ endv,
    float* __restrict__ out)
{
  int b = blockIdx.x;
  int tid = threadIdx.x;
  __shared__ float tr[Lx * Lx];
  __shared__ float al[2][Lx];
  __shared__ float norm_s;
  for (int i = tid; i < Lx * Lx; i += 64) tr[i] = trans[i];
  if (tid < Lx) al[0][tid] = logits[b * Lx + tid] + startv[tid];
  __syncthreads();
  int cur = 0;
  for (int t = 1; t < Sx; ++t) {
    if (tid < Lx) {
      int to = tid;
      float v[Lx];
      float mx = -1e30f;
#pragma unroll
      for (int f = 0; f < Lx; ++f) { v[f] = al[cur][f] + tr[f * Lx + to]; mx = fmaxf(mx, v[f]); }
      float sum = 0.f;
#pragma unroll
      for (int f = 0; f < Lx; ++f) sum += expf(v[f] - mx);
      float nv = mx + logf(sum) + logits[((size_t)t * Bx + b) * Lx + to];
      int m = mask[b * Sx + t];
      al[1 - cur][to] = (m > 0) ? nv : al[cur][to];
    }
    __syncthreads();
    cur ^= 1;
  }
  if (tid == 0) {
    float mx = -1e30f;
    for (int l = 0; l < Lx; ++l) mx = fmaxf(mx, al[cur][l] + endv[l]);
    float s = 0.f;
    for (int l = 0; l < Lx; ++l) s += expf(al[cur][l] + endv[l] - mx);
    norm_s = mx + logf(s);
  }
  __syncthreads();
  const int* lab = labels + b * Sx;
  const int* msk = mask + b * Sx;
  float part = 0.f;
  int msum = 0;
  for (int t = tid; t < Sx; t += 64) {
    int m = msk[t];
    int tg = lab[t];
    if (m > 0) {
      part += logits[((size_t)t * Bx + b) * Lx + tg];
      if (t >= 1) part += tr[lab[t - 1] * Lx + tg];
      msum++;
    }
  }
#pragma unroll
  for (int o = 32; o > 0; o >>= 1) {
    part += __shfl_down(part, o, 64);
    msum += __shfl_down(msum, o, 64);
  }
  if (tid == 0) {
    float gold = part + startv[lab[0]] + endv[lab[msum - 1]];
    atomicAdd(out, (norm_s - gold) * (1.0f / 32.0f));
  }
}

// ---------------- launch ----------------

extern "C" void kernel_launch(void* const* d_in, const int* in_sizes, int n_in,
                              void* d_out, int out_size, void* d_ws, size_t ws_size,
                              hipStream_t stream)
{
  const float* x      = (const float*)d_in[0];
  const int* labels   = (const int*)d_in[1];
  const int* mask     = (const int*)d_in[2];
  const float* wih0f  = (const float*)d_in[3];
  const float* whh0f  = (const float*)d_in[4];
  const float* bih0f  = (const float*)d_in[5];
  const float* bhh0f  = (const float*)d_in[6];
  const float* wih0b  = (const float*)d_in[7];
  const float* whh0b  = (const float*)d_in[8];
  const float* bih0b  = (const float*)d_in[9];
  const float* bhh0b  = (const float*)d_in[10];
  const float* wih1f  = (const float*)d_in[11];
  const float* whh1f  = (const float*)d_in[12];
  const float* bih1f  = (const float*)d_in[13];
  const float* bhh1f  = (const float*)d_in[14];
  const float* wih1b  = (const float*)d_in[15];
  const float* whh1b  = (const float*)d_in[16];
  const float* bih1b  = (const float*)d_in[17];
  const float* bhh1b  = (const float*)d_in[18];
  const float* fcw    = (const float*)d_in[19];
  const float* fcb    = (const float*)d_in[20];
  const float* transm = (const float*)d_in[21];
  const float* startv = (const float*)d_in[22];
  const float* endv   = (const float*)d_in[23];

  char* p = (char*)d_ws;
  auto alloc = [&](size_t bytes) -> char* {
    char* r = p;
    p += (bytes + 255) & ~((size_t)255);
    return r;
  };

  unsigned short* x_bf    = (unsigned short*)alloc((size_t)Rx * Hx * 2);
  unsigned short* wih0f_b = (unsigned short*)alloc((size_t)Gx * Hx * 2);
  unsigned short* wih0b_b = (unsigned short*)alloc((size_t)Gx * Hx * 2);
  unsigned short* whh0f_b = (unsigned short*)alloc((size_t)Gx * Hx * 2);
  unsigned short* whh0b_b = (unsigned short*)alloc((size_t)Gx * Hx * 2);
  unsigned short* wih1f_b = (unsigned short*)alloc((size_t)Gx * 1024 * 2);
  unsigned short* wih1b_b = (unsigned short*)alloc((size_t)Gx * 1024 * 2);
  unsigned short* whh1f_b = (unsigned short*)alloc((size_t)Gx * Hx * 2);
  unsigned short* whh1b_b = (unsigned short*)alloc((size_t)Gx * Hx * 2);
  float* bias0f = (float*)alloc(Gx * 4);
  float* bias0b = (float*)alloc(Gx * 4);
  float* bias1f = (float*)alloc(Gx * 4);
  float* bias1b = (float*)alloc(Gx * 4);
  unsigned short* xw_f = (unsigned short*)alloc((size_t)Rx * Gx * 2);
  unsigned short* xw_b = (unsigned short*)alloc((size_t)Rx * Gx * 2);
  unsigned short* h0T  = (unsigned short*)alloc((size_t)2 * Sx * 16384 * 2);
  unsigned short* h1T  = (unsigned short*)alloc((size_t)2 * Sx * 16384 * 2);
  unsigned short* h0rows = (unsigned short*)alloc((size_t)Rx * 1024 * 2);
  float* logits = (float*)alloc((size_t)Rx * Lx * 4);
  unsigned int* flags = (unsigned int*)alloc(2 * 2 * 32 * 32 * 4);  // [layer][dir][ws][32]

  if ((size_t)(p - (char*)d_ws) > ws_size) return;

  hipMemsetAsync(flags, 0, 2 * 2 * 32 * 32 * 4, stream);

  // pack & cast
  k_pack_x<<<(Rx * Hx) / 256, 256, 0, stream>>>(x, x_bf);
  k_cast<<<(Gx * Hx) / 256, 256, 0, stream>>>(wih0f, wih0f_b, Gx * Hx);
  k_cast<<<(Gx * Hx) / 256, 256, 0, stream>>>(wih0b, wih0b_b, Gx * Hx);
  k_cast<<<(Gx * Hx) / 256, 256, 0, stream>>>(whh0f, whh0f_b, Gx * Hx);
  k_cast<<<(Gx * Hx) / 256, 256, 0, stream>>>(whh0b, whh0b_b, Gx * Hx);
  k_cast<<<(Gx * 1024) / 256, 256, 0, stream>>>(wih1f, wih1f_b, Gx * 1024);
  k_cast<<<(Gx * 1024) / 256, 256, 0, stream>>>(wih1b, wih1b_b, Gx * 1024);
  k_cast<<<(Gx * Hx) / 256, 256, 0, stream>>>(whh1f, whh1f_b, Gx * Hx);
  k_cast<<<(Gx * Hx) / 256, 256, 0, stream>>>(whh1b, whh1b_b, Gx * Hx);
  k_add2<<<Gx / 256, 256, 0, stream>>>(bih0f, bhh0f, bias0f, Gx);
  k_add2<<<Gx / 256, 256, 0, stream>>>(bih0b, bhh0b, bias0b, Gx);
  k_add2<<<Gx / 256, 256, 0, stream>>>(bih1f, bhh1f, bias1f, Gx);
  k_add2<<<Gx / 256, 256, 0, stream>>>(bih1b, bhh1b, bias1b, Gx);

  // layer 0
  k_gemm<<<dim3(Gx / 128, Rx / 128), 256, 0, stream>>>(x_bf, wih0f_b, bias0f, xw_f, Rx, Gx, Hx);
  k_gemm<<<dim3(Gx / 128, Rx / 128), 256, 0, stream>>>(x_bf, wih0b_b, bias0b, xw_b, Rx, Gx, Hx);
  k_lstm<<<64, 64, 0, stream>>>(xw_f, xw_b, whh0f_b, whh0b_b, h0T, flags);

  // repack h0 tiled -> rows for layer-1 GEMM
  k_repack<<<4096, 256, 0, stream>>>(h0T, h0rows);

  // layer 1
  k_gemm<<<dim3(Gx / 128, Rx / 128), 256, 0, stream>>>(h0rows, wih1f_b, bias1f, xw_f, Rx, Gx, 1024);
  k_gemm<<<dim3(Gx / 128, Rx / 128), 256, 0, stream>>>(h0rows, wih1b_b, bias1b, xw_b, Rx, Gx, 1024);
  k_lstm<<<64, 64, 0, stream>>>(xw_f, xw_b, whh1f_b, whh1b_b, h1T, flags + 2 * 32 * 32);

  // FC + CRF
  k_fc<<<Rx, 256, 0, stream>>>(h1T, fcw, fcb, logits);
  hipMemsetAsync(d_out, 0, 4, stream);
  k_crf<<<Bx, 64, 0, stream>>>(logits, labels, mask, transm, startv, endv, (float*)d_out);
}